// Round 1
// baseline (1326.235 us; speedup 1.0000x reference)
//
#include <hip/hip_runtime.h>
#include <stdint.h>

#define SEQ   2048
#define BATCH 2
#define HD    4096
#define NH    32
#define NKV   2
#define HDIM  128
#define NT    (SEQ*BATCH)   // 4096 tokens
#define KVC   (NKV*HDIM)    // 256

typedef short  bf16x8 __attribute__((ext_vector_type(8)));
typedef float  f32x4  __attribute__((ext_vector_type(4)));

__device__ __forceinline__ float bf2f(unsigned short u){
  union { unsigned int i; float f; } v; v.i = ((unsigned int)u) << 16; return v.f;
}
__device__ __forceinline__ unsigned short f2bf(float f){
  union { float f; unsigned int i; } v; v.f = f;
  unsigned int r = v.i + 0x7FFFu + ((v.i >> 16) & 1u);
  return (unsigned short)(r >> 16);
}

// async global->LDS, 16B per lane; LDS dest is wave-uniform base + lane*16
__device__ __forceinline__ void gload_lds16(const void* g, void* lds){
  __builtin_amdgcn_global_load_lds(
      (const __attribute__((address_space(1))) unsigned int*)(size_t)g,
      (__attribute__((address_space(3))) unsigned int*)(unsigned int)(size_t)lds,
      16, 0, 0);
}

// ---------------- cast fp32 -> bf16 (vectorized) ----------------
__global__ void k_cast(const float* __restrict__ in, unsigned short* __restrict__ out, int n4){
  int i = blockIdx.x * blockDim.x + threadIdx.x;
  if (i >= n4) return;
  float4 v = ((const float4*)in)[i];
  ushort4 o; o.x = f2bf(v.x); o.y = f2bf(v.y); o.z = f2bf(v.z); o.w = f2bf(v.w);
  ((ushort4*)out)[i] = o;
}

// ---------------- W (KxN fp32) -> W^T (NxK bf16), LDS tiled ----------------
__global__ void k_transpose(const float* __restrict__ W, unsigned short* __restrict__ WT,
                            int K, int N){
  __shared__ float t[32][33];
  int n0 = blockIdx.x * 32, k0 = blockIdx.y * 32;
  int tx = threadIdx.x, ty = threadIdx.y;
  t[ty][tx] = W[(size_t)(k0 + ty) * N + n0 + tx];
  __syncthreads();
  WT[(size_t)(n0 + ty) * K + k0 + tx] = f2bf(t[tx][ty]);
}

// ---------------- GEMM: C[MxN] = A[MxK] * BT[NxK]^T + bias  (m97 structure) ----------------
template<bool OUTF32>
__global__ __launch_bounds__(256) void k_gemm(
    const unsigned short* __restrict__ A,
    const unsigned short* __restrict__ BT,
    const float* __restrict__ bias,
    void* __restrict__ C, int M, int N, int K)
{
  __shared__ unsigned short As[128*32];
  __shared__ unsigned short Bs[128*32];
  const int tid  = threadIdx.x;
  const int lane = tid & 63;
  const int w    = tid >> 6;
  const int l4   = lane >> 4, l15 = lane & 15;
  const int wm   = (w >> 1) * 64, wn = (w & 1) * 64;
  const size_t bm = (size_t)blockIdx.y * 128, bn = (size_t)blockIdx.x * 128;

  f32x4 acc[4][4] = {};
  const int scol = (lane & 3) * 8;   // element offset within a 32-elem row

  for (int k0 = 0; k0 < K; k0 += 32) {
    #pragma unroll
    for (int j = 0; j < 2; ++j) {
      const int r = w*32 + j*16 + (lane >> 2);
      gload_lds16(A  + (bm + r) * (size_t)K + k0 + scol, As + (size_t)(w*32 + j*16) * 32);
      gload_lds16(BT + (bn + r) * (size_t)K + k0 + scol, Bs + (size_t)(w*32 + j*16) * 32);
    }
    __syncthreads();
    bf16x8 af[4], bfr[4];
    #pragma unroll
    for (int m = 0; m < 4; ++m)
      af[m] = *(const bf16x8*)(As + (wm + m*16 + l15)*32 + l4*8);
    #pragma unroll
    for (int n = 0; n < 4; ++n)
      bfr[n] = *(const bf16x8*)(Bs + (wn + n*16 + l15)*32 + l4*8);
    #pragma unroll
    for (int m = 0; m < 4; ++m)
      #pragma unroll
      for (int n = 0; n < 4; ++n)
        acc[m][n] = __builtin_amdgcn_mfma_f32_16x16x32_bf16(af[m], bfr[n], acc[m][n], 0, 0, 0);
    __syncthreads();
  }

  #pragma unroll
  for (int n = 0; n < 4; ++n) {
    const size_t col = bn + wn + n*16 + l15;
    const float bv = bias ? bias[col] : 0.0f;
    #pragma unroll
    for (int m = 0; m < 4; ++m) {
      const size_t row0 = bm + wm + m*16 + l4*4;
      #pragma unroll
      for (int r = 0; r < 4; ++r) {
        float v = acc[m][n][r] + bv;
        if (OUTF32) ((float*)C)[(row0 + r) * (size_t)N + col] = v;
        else ((unsigned short*)C)[(row0 + r) * (size_t)N + col] = f2bf(v);
      }
    }
  }
}

// ---------------- RoPE + layout: [tok][cols] -> [b][slab][s][d], optional scale ----------------
__global__ void k_rope(const unsigned short* __restrict__ In, const float* __restrict__ rope,
                       unsigned short* __restrict__ Out, int ncols, int nslab, int psh, float sc)
{
  int idx = blockIdx.x * 256 + threadIdx.x;
  int npair = ncols >> 1;
  if (idx >= NT * npair) return;
  int t = idx >> psh, pr = idx & (npair - 1);
  int colp = pr * 2, h = colp >> 7, d = colp & 127;
  int s = t >> 1, b = t & 1;
  float x0 = bf2f(In[(size_t)t * ncols + colp]);
  float x1 = bf2f(In[(size_t)t * ncols + colp + 1]);
  float o0 = x0, o1 = x1;
  if (d < 64) {
    int i2 = d >> 1;
    float cr = rope[((size_t)s * 32 + i2) * 2 + 0];
    float ci = rope[((size_t)s * 32 + i2) * 2 + 1];
    o0 = x0 * cr - x1 * ci;
    o1 = x1 * cr + x0 * ci;
  }
  size_t dst = ((size_t)(b * nslab + h) * SEQ + s) * HDIM + d;
  Out[dst]     = f2bf(o0 * sc);
  Out[dst + 1] = f2bf(o1 * sc);
}

// ---------------- V: [tok][256] -> V^T [b][kv][d][s] ----------------
__global__ void k_vt(const unsigned short* __restrict__ In, unsigned short* __restrict__ Out){
  int idx = blockIdx.x * 256 + threadIdx.x;
  if (idx >= NT * KVC) return;
  int t = idx >> 8, cp = idx & 255;
  int kv = cp >> 7, d = cp & 127;
  int s = t >> 1, b = t & 1;
  Out[((size_t)(b * NKV + kv) * HDIM + d) * SEQ + s] = In[idx];
}

// ---------------- causal flash attention, 1 wave / 16 q-rows ----------------
__global__ __launch_bounds__(64) void k_attn(
    const unsigned short* __restrict__ Q,    // [b][h][s][d], pre-scaled by 1/sqrt(d)
    const unsigned short* __restrict__ Kk,   // [b][kv][s][d]
    const unsigned short* __restrict__ Vt,   // [b][kv][d][s]
    unsigned short* __restrict__ Ctx)        // [tok][4096]
{
  const int lane = threadIdx.x;
  const int g = lane >> 4, c = lane & 15;
  const int bh = blockIdx.y;
  const int b = bh >> 5, h = bh & 31;
  const int q0 = blockIdx.x * 16;
  const unsigned short* Qb = Q  + ((size_t)(b * NH  + h)        * SEQ + q0) * HDIM;
  const unsigned short* Kb = Kk + ((size_t)(b * NKV + (h >> 4)) * SEQ) * HDIM;
  const unsigned short* Vb = Vt + ((size_t)(b * NKV + (h >> 4)) * HDIM) * SEQ;

  __shared__ unsigned short P[16 * 40];   // padded: stride 40 elems (80B)

  bf16x8 qf[4];
  #pragma unroll
  for (int kk = 0; kk < 4; ++kk)
    qf[kk] = *(const bf16x8*)(Qb + (size_t)c * HDIM + kk*32 + g*8);

  f32x4 of[8] = {};
  float mrun[4] = {-1e30f, -1e30f, -1e30f, -1e30f};
  float lrun[4] = {};

  const int tend = q0 + 16;
  for (int t0 = 0; t0 < tend; t0 += 32) {
    f32x4 s0 = {}, s1 = {};
    #pragma unroll
    for (int kk = 0; kk < 4; ++kk) {
      bf16x8 kf = *(const bf16x8*)(Kb + (size_t)(t0 + c) * HDIM + kk*32 + g*8);
      s0 = __builtin_amdgcn_mfma_f32_16x16x32_bf16(qf[kk], kf, s0, 0, 0, 0);
    }
    const bool act1 = (t0 + 16) < tend;
    if (act1) {
      #pragma unroll
      for (int kk = 0; kk < 4; ++kk) {
        bf16x8 kf = *(const bf16x8*)(Kb + (size_t)(t0 + 16 + c) * HDIM + kk*32 + g*8);
        s1 = __builtin_amdgcn_mfma_f32_16x16x32_bf16(qf[kk], kf, s1, 0, 0, 0);
      }
    }
    // mask + online softmax (rows live in lanes with same g; cols across c)
    float mloc[4], al[4], ps[4];
    #pragma unroll
    for (int r = 0; r < 4; ++r) {
      const int qg = q0 + g*4 + r;
      if (t0 + c > qg)                    s0[r] = -1e30f;
      if (!act1 || t0 + 16 + c > qg)      s1[r] = -1e30f;
      mloc[r] = fmaxf(s0[r], s1[r]);
    }
    #pragma unroll
    for (int msk = 1; msk < 16; msk <<= 1)
      #pragma unroll
      for (int r = 0; r < 4; ++r)
        mloc[r] = fmaxf(mloc[r], __shfl_xor(mloc[r], msk, 64));
    #pragma unroll
    for (int r = 0; r < 4; ++r) {
      const float mn = fmaxf(mrun[r], mloc[r]);
      al[r] = __expf(mrun[r] - mn);
      mrun[r] = mn;
      const float p0 = __expf(s0[r] - mn);
      const float p1 = __expf(s1[r] - mn);
      ps[r] = p0 + p1;
      P[(g*4 + r)*40 + c]      = f2bf(p0);
      P[(g*4 + r)*40 + 16 + c] = f2bf(p1);
    }
    #pragma unroll
    for (int msk = 1; msk < 16; msk <<= 1)
      #pragma unroll
      for (int r = 0; r < 4; ++r)
        ps[r] += __shfl_xor(ps[r], msk, 64);
    #pragma unroll
    for (int r = 0; r < 4; ++r)
      lrun[r] = lrun[r] * al[r] + ps[r];
    #pragma unroll
    for (int d8 = 0; d8 < 8; ++d8)
      #pragma unroll
      for (int r = 0; r < 4; ++r)
        of[d8][r] *= al[r];
    __syncthreads();
    // PV: A = P (row=q=c, k=t contiguous), B = V^T rows (col=d, k=t contiguous)
    bf16x8 pa = *(const bf16x8*)(P + c*40 + g*8);
    #pragma unroll
    for (int d8 = 0; d8 < 8; ++d8) {
      bf16x8 vf = *(const bf16x8*)(Vb + (size_t)(d8*16 + c) * SEQ + t0 + g*8);
      of[d8] = __builtin_amdgcn_mfma_f32_16x16x32_bf16(pa, vf, of[d8], 0, 0, 0);
    }
    __syncthreads();
  }

  #pragma unroll
  for (int d8 = 0; d8 < 8; ++d8) {
    #pragma unroll
    for (int r = 0; r < 4; ++r) {
      const int s = q0 + g*4 + r;
      const float v = of[d8][r] / lrun[r];
      Ctx[((size_t)(s * BATCH + b)) * HD + (size_t)h * HDIM + d8*16 + c] = f2bf(v);
    }
  }
}

extern "C" void kernel_launch(void* const* d_in, const int* in_sizes, int n_in,
                              void* d_out, int out_size, void* d_ws, size_t ws_size,
                              hipStream_t stream)
{
  const float* hs   = (const float*)d_in[0];
  const float* rope = (const float*)d_in[1];
  const float* Wq   = (const float*)d_in[2];
  const float* bq   = (const float*)d_in[3];
  const float* Wk   = (const float*)d_in[4];
  const float* bk   = (const float*)d_in[5];
  const float* Wv   = (const float*)d_in[6];
  const float* bv   = (const float*)d_in[7];
  const float* Wo   = (const float*)d_in[8];

  char* ws = (char*)d_ws;
  const size_t MB = (size_t)1 << 20;
  // lifetimes allow: Ctx aliases Xbf (X dead after V-GEMM); Qattn aliases WqT (dead after Q-GEMM)
  unsigned short* Xbf  = (unsigned short*)(ws);             // 32MB
  unsigned short* Ctx  = Xbf;
  unsigned short* WqT  = (unsigned short*)(ws + 32*MB);     // 32MB
  unsigned short* Qa   = WqT;
  unsigned short* WkT  = (unsigned short*)(ws + 64*MB);     // 2MB
  unsigned short* WvT  = (unsigned short*)(ws + 66*MB);     // 2MB
  unsigned short* WoT  = (unsigned short*)(ws + 68*MB);     // 32MB
  unsigned short* Qtmp = (unsigned short*)(ws + 100*MB);    // 32MB
  unsigned short* Ktmp = (unsigned short*)(ws + 132*MB);    // 2MB
  unsigned short* Vtmp = (unsigned short*)(ws + 134*MB);    // 2MB
  unsigned short* Ka   = (unsigned short*)(ws + 136*MB);    // 2MB
  unsigned short* VTa  = (unsigned short*)(ws + 138*MB);    // 2MB -> total 140MB

  k_cast<<<(NT*HD/4 + 255)/256, 256, 0, stream>>>(hs, Xbf, NT*HD/4);

  dim3 tb(32, 32);
  k_transpose<<<dim3(HD/32,  HD/32), tb, 0, stream>>>(Wq, WqT, HD, HD);
  k_transpose<<<dim3(KVC/32, HD/32), tb, 0, stream>>>(Wk, WkT, HD, KVC);
  k_transpose<<<dim3(KVC/32, HD/32), tb, 0, stream>>>(Wv, WvT, HD, KVC);
  k_transpose<<<dim3(HD/32,  HD/32), tb, 0, stream>>>(Wo, WoT, HD, HD);

  k_gemm<false><<<dim3(HD/128,  NT/128), 256, 0, stream>>>(Xbf, WqT, bq, Qtmp, NT, HD,  HD);
  k_gemm<false><<<dim3(KVC/128, NT/128), 256, 0, stream>>>(Xbf, WkT, bk, Ktmp, NT, KVC, HD);
  k_gemm<false><<<dim3(KVC/128, NT/128), 256, 0, stream>>>(Xbf, WvT, bv, Vtmp, NT, KVC, HD);

  const float sc = 0.08838834764831845f;  // 1/sqrt(128)
  k_rope<<<(NT*(HD/2)  + 255)/256, 256, 0, stream>>>(Qtmp, rope, Qa, HD,  NH,  11, sc);
  k_rope<<<(NT*(KVC/2) + 255)/256, 256, 0, stream>>>(Ktmp, rope, Ka, KVC, NKV, 7, 1.0f);
  k_vt  <<<(NT*KVC     + 255)/256, 256, 0, stream>>>(Vtmp, VTa);

  k_attn<<<dim3(SEQ/16, NH*BATCH), 64, 0, stream>>>(Qa, Ka, VTa, Ctx);

  k_gemm<true><<<dim3(HD/128, NT/128), 256, 0, stream>>>(Ctx, WoT, nullptr, d_out, NT, HD, HD);
}